// Round 1
// baseline (9968.165 us; speedup 1.0000x reference)
//
#include <hip/hip_runtime.h>
#include <math.h>

// FERNN forward, fp32 baseline.
// Shapes: u (4,8,3,64,64); V=9 velocities; HID=64; T=8; H=W=64.
// Output (V,B,C,T,H,W) fp32, 75,497,472 elements.
//
// Per step t:
//   e1 = relu(bn(conv5x5_zp(u_t, w_u1)))          (4,32,64,64)
//   e2 = relu(bn(conv3x3_zp(e1,  w_u2)))          (4,64,64,64)
//   x  = relu(bn(conv3x3_zp(e2,  w_u3)))          (4,64,64,64)
//   h0 = tanh(x + circconv3x3_shift(h0_old, w_h0))        (4,9,64,64,64)
//   up = relu(bn(conv3x3_zp(h0, w_ul)))                   (4,9,64,64,64)
//   h1 = tanh(up + circconv3x3_shift(h1_old, w_h1)) -> d_out slice t
// shift fused into conv read offsets: in[(y+vy+dy-1)&63, (x+vx+dx-1)&63].

#define BN_SCALE 0.9999950000374997f  // 1/sqrt(1+1e-5)

// ---------------------------------------------------------------- conv1 5x5
__global__ __launch_bounds__(256) void conv5x5_enc(
    const float* __restrict__ u, int ub_stride,
    const float* __restrict__ w,
    const float* __restrict__ gg, const float* __restrict__ bb,
    float* __restrict__ out)
{
  __shared__ float tile[3 * 144];   // [3][12][12]
  __shared__ float ws[2400];        // (32,3,5,5)
  const int tid = threadIdx.x;
  const int b = blockIdx.y;
  const int t8 = blockIdx.x;
  const int y0 = (t8 >> 3) * 8, x0 = (t8 & 7) * 8;
  const float* ub = u + (size_t)b * ub_stride;
  for (int i = tid; i < 3 * 144; i += 256) {
    int c = i / 144, rem = i % 144;
    int r = rem / 12, cc = rem % 12;
    int y = y0 + r - 2, x = x0 + cc - 2;
    float v = 0.f;
    if (y >= 0 && y < 64 && x >= 0 && x < 64) v = ub[c * 4096 + y * 64 + x];
    tile[i] = v;
  }
  for (int i = tid; i < 2400; i += 256) ws[i] = w[i];
  __syncthreads();
  const int px = tid & 63;
  const int py = px >> 3, pxx = px & 7;
  const int ocb = (tid >> 6) * 8;   // 4 groups of 8 out-channels (32 total)
  float acc[8];
#pragma unroll
  for (int i = 0; i < 8; i++) acc[i] = 0.f;
  for (int c = 0; c < 3; c++) {
    float in25[25];
#pragma unroll
    for (int ky = 0; ky < 5; ky++)
#pragma unroll
      for (int kx = 0; kx < 5; kx++)
        in25[ky * 5 + kx] = tile[c * 144 + (py + ky) * 12 + (pxx + kx)];
#pragma unroll
    for (int o = 0; o < 8; o++) {
      float s = 0.f;
#pragma unroll
      for (int k = 0; k < 25; k++)
        s += ws[(ocb + o) * 75 + c * 25 + k] * in25[k];
      acc[o] += s;
    }
  }
  float* ob = out + (size_t)b * 32 * 4096 + (y0 + py) * 64 + (x0 + pxx);
#pragma unroll
  for (int o = 0; o < 8; o++) {
    int oc = ocb + o;
    float v = acc[o] * (gg[oc] * BN_SCALE) + bb[oc];
    ob[oc * 4096] = v > 0.f ? v : 0.f;
  }
}

// ------------------------------------------- generic 3x3 zero-pad + bn+relu
template <int CIN>
__global__ __launch_bounds__(256) void conv3x3_bnrelu(
    const float* __restrict__ in, const float* __restrict__ w,
    const float* __restrict__ gg, const float* __restrict__ bb,
    float* __restrict__ out)
{
  __shared__ float tile[CIN * 100];      // [CIN][10][10]
  __shared__ float ws[8 * 64 * 12];      // chunk: [8 cin][64 oc][12 (9 used)]
  const int tid = threadIdx.x;
  const int n = blockIdx.y;
  const int t8 = blockIdx.x;
  const int y0 = (t8 >> 3) * 8, x0 = (t8 & 7) * 8;
  const float* inb = in + (size_t)n * CIN * 4096;

  for (int i = tid; i < CIN * 100; i += 256) {
    int cin = i / 100, rem = i % 100;
    int r = rem / 10, c = rem % 10;
    int y = y0 + r - 1, x = x0 + c - 1;
    float v = 0.f;
    if (y >= 0 && y < 64 && x >= 0 && x < 64) v = inb[cin * 4096 + y * 64 + x];
    tile[i] = v;
  }

  const int px = tid & 63;
  const int py = px >> 3, pxx = px & 7;
  const int ocb = (tid >> 6) * 16;
  float acc[16];
#pragma unroll
  for (int i = 0; i < 16; i++) acc[i] = 0.f;

  for (int cin0 = 0; cin0 < CIN; cin0 += 8) {
    __syncthreads();
    for (int i = tid; i < 8 * 64 * 9; i += 256) {
      int ci = i / 576, rem = i % 576;
      int oc = rem / 9, k = rem % 9;
      ws[ci * 768 + oc * 12 + k] = w[(oc * CIN + cin0 + ci) * 9 + k];
    }
    __syncthreads();
#pragma unroll
    for (int ci = 0; ci < 8; ci++) {
      const int cin = cin0 + ci;
      float in9[9];
#pragma unroll
      for (int ky = 0; ky < 3; ky++)
#pragma unroll
        for (int kx = 0; kx < 3; kx++)
          in9[ky * 3 + kx] = tile[cin * 100 + (py + ky) * 10 + (pxx + kx)];
#pragma unroll
      for (int o = 0; o < 16; o++) {
        const float4 w0 = *(const float4*)&ws[ci * 768 + (ocb + o) * 12];
        const float4 w1 = *(const float4*)&ws[ci * 768 + (ocb + o) * 12 + 4];
        const float w8 = ws[ci * 768 + (ocb + o) * 12 + 8];
        acc[o] += w0.x * in9[0] + w0.y * in9[1] + w0.z * in9[2] + w0.w * in9[3]
                + w1.x * in9[4] + w1.y * in9[5] + w1.z * in9[6] + w1.w * in9[7]
                + w8 * in9[8];
      }
    }
  }

  float* ob = out + (size_t)n * 64 * 4096 + (y0 + py) * 64 + (x0 + pxx);
#pragma unroll
  for (int o = 0; o < 16; o++) {
    int oc = ocb + o;
    float v = acc[o] * (gg[oc] * BN_SCALE) + bb[oc];
    ob[oc * 4096] = v > 0.f ? v : 0.f;
  }
}

// ---------------- recurrent update: out = tanh(add + circconv_shift(hin, w))
__global__ __launch_bounds__(256) void rnn_update(
    const float* __restrict__ hin, int hin_b, int hin_v, int hin_c,
    const float* __restrict__ add, int add_b, int add_v, int add_c,
    const float* __restrict__ w,
    float* __restrict__ out, int out_b, int out_v, int out_c,
    int zero_in)
{
  __shared__ float tile[64 * 100];
  __shared__ float ws[8 * 64 * 12];
  const int tid = threadIdx.x;
  const int bv = blockIdx.y;
  const int b = bv / 9, v = bv % 9;
  const int vy = v / 3 - 1, vx = v % 3 - 1;
  const int t8 = blockIdx.x;
  const int y0 = (t8 >> 3) * 8, x0 = (t8 & 7) * 8;

  const int px = tid & 63;
  const int py = px >> 3, pxx = px & 7;
  const int ocb = (tid >> 6) * 16;

  const float* addb = add + (size_t)b * add_b + (size_t)v * add_v
                      + (y0 + py) * 64 + (x0 + pxx);
  float* ob = out + (size_t)b * out_b + (size_t)v * out_v
              + (y0 + py) * 64 + (x0 + pxx);

  if (zero_in) {
#pragma unroll
    for (int o = 0; o < 16; o++) {
      int oc = ocb + o;
      ob[(size_t)oc * out_c] = tanhf(addb[(size_t)oc * add_c]);
    }
    return;
  }

  const float* hb = hin + (size_t)b * hin_b + (size_t)v * hin_v;
  for (int i = tid; i < 6400; i += 256) {
    int cin = i / 100, rem = i % 100;
    int r = rem / 10, c = rem % 10;
    int y = (y0 + r - 1 + vy + 64) & 63;
    int x = (x0 + c - 1 + vx + 64) & 63;
    tile[i] = hb[(size_t)cin * hin_c + y * 64 + x];
  }

  float acc[16];
#pragma unroll
  for (int i = 0; i < 16; i++) acc[i] = 0.f;

  for (int cin0 = 0; cin0 < 64; cin0 += 8) {
    __syncthreads();
    for (int i = tid; i < 8 * 64 * 9; i += 256) {
      int ci = i / 576, rem = i % 576;
      int oc = rem / 9, k = rem % 9;
      ws[ci * 768 + oc * 12 + k] = w[(oc * 64 + cin0 + ci) * 9 + k];
    }
    __syncthreads();
#pragma unroll
    for (int ci = 0; ci < 8; ci++) {
      const int cin = cin0 + ci;
      float in9[9];
#pragma unroll
      for (int ky = 0; ky < 3; ky++)
#pragma unroll
        for (int kx = 0; kx < 3; kx++)
          in9[ky * 3 + kx] = tile[cin * 100 + (py + ky) * 10 + (pxx + kx)];
#pragma unroll
      for (int o = 0; o < 16; o++) {
        const float4 w0 = *(const float4*)&ws[ci * 768 + (ocb + o) * 12];
        const float4 w1 = *(const float4*)&ws[ci * 768 + (ocb + o) * 12 + 4];
        const float w8 = ws[ci * 768 + (ocb + o) * 12 + 8];
        acc[o] += w0.x * in9[0] + w0.y * in9[1] + w0.z * in9[2] + w0.w * in9[3]
                + w1.x * in9[4] + w1.y * in9[5] + w1.z * in9[6] + w1.w * in9[7]
                + w8 * in9[8];
      }
    }
  }

#pragma unroll
  for (int o = 0; o < 16; o++) {
    int oc = ocb + o;
    ob[(size_t)oc * out_c] = tanhf(acc[o] + addb[(size_t)oc * add_c]);
  }
}

// --------------------------------------------------------------------- host
extern "C" void kernel_launch(void* const* d_in, const int* in_sizes, int n_in,
                              void* d_out, int out_size, void* d_ws, size_t ws_size,
                              hipStream_t stream) {
  (void)in_sizes; (void)n_in; (void)out_size; (void)ws_size;
  const float* u    = (const float*)d_in[0];
  const float* w_u1 = (const float*)d_in[1];
  const float* g1   = (const float*)d_in[2];
  const float* b1   = (const float*)d_in[3];
  const float* w_u2 = (const float*)d_in[4];
  const float* g2   = (const float*)d_in[5];
  const float* b2   = (const float*)d_in[6];
  const float* w_u3 = (const float*)d_in[7];
  const float* g3   = (const float*)d_in[8];
  const float* b3   = (const float*)d_in[9];
  const float* w_ul = (const float*)d_in[10];
  const float* gul  = (const float*)d_in[11];
  const float* bul  = (const float*)d_in[12];
  const float* w_h0 = (const float*)d_in[13];
  const float* w_h1 = (const float*)d_in[14];
  float* out = (float*)d_out;

  float* wsf = (float*)d_ws;
  float* e1  = wsf;                  // 4*32*4096   = 524288
  float* e2  = e1 + 524288;          // 4*64*4096   = 1048576
  float* xb  = e2 + 1048576;         // 4*64*4096   = 1048576
  float* up  = xb + 1048576;         // 36*64*4096  = 9437184
  float* h0a = up + 9437184;         // 9437184
  float* h0b = h0a + 9437184;        // 9437184   total ~124 MB

  const int H0B = 9 * 64 * 4096, H0V = 64 * 4096, H0C = 4096;
  const int OB = 64 * 8 * 4096, OV = 4 * 64 * 8 * 4096, OC = 8 * 4096;

  dim3 blk(256);
  for (int t = 0; t < 8; t++) {
    float* h0_old = (t & 1) ? h0b : h0a;
    float* h0_new = (t & 1) ? h0a : h0b;

    conv5x5_enc<<<dim3(64, 4), blk, 0, stream>>>(
        u + (size_t)t * 3 * 4096, 8 * 3 * 4096, w_u1, g1, b1, e1);
    conv3x3_bnrelu<32><<<dim3(64, 4), blk, 0, stream>>>(e1, w_u2, g2, b2, e2);
    conv3x3_bnrelu<64><<<dim3(64, 4), blk, 0, stream>>>(e2, w_u3, g3, b3, xb);

    rnn_update<<<dim3(64, 36), blk, 0, stream>>>(
        h0_old, H0B, H0V, H0C,
        xb, 64 * 4096, 0, 4096,
        w_h0,
        h0_new, H0B, H0V, H0C,
        t == 0 ? 1 : 0);

    conv3x3_bnrelu<64><<<dim3(64, 36), blk, 0, stream>>>(h0_new, w_ul, gul, bul, up);

    rnn_update<<<dim3(64, 36), blk, 0, stream>>>(
        out + (size_t)(t - 1) * 4096, OB, OV, OC,
        up, 9 * 64 * 4096, 64 * 4096, 4096,
        w_h1,
        out + (size_t)t * 4096, OB, OV, OC,
        t == 0 ? 1 : 0);
  }
}

// Round 3
// 1658.624 us; speedup vs baseline: 6.0099x; 6.0099x over previous
//
#include <hip/hip_runtime.h>
#include <hip/hip_bf16.h>
#include <math.h>

typedef __attribute__((ext_vector_type(8))) short short8;
typedef __attribute__((ext_vector_type(4))) float f32x4;

#define BN_SCALE 0.9999950000374997f  // 1/sqrt(1+1e-5)

__device__ __forceinline__ unsigned short f2bf(float f) {
  union { float f; unsigned u; } v; v.f = f;
  unsigned r = v.u + 0x7fff + ((v.u >> 16) & 1);
  return (unsigned short)(r >> 16);
}
__device__ __forceinline__ float bf2f(unsigned short h) {
  union { unsigned u; float f; } v; v.u = ((unsigned)h) << 16;
  return v.f;
}
__device__ __forceinline__ float fast_tanh(float x) {
  float e = __expf(2.0f * x);
  return 1.0f - 2.0f / (e + 1.0f);
}

// ---------------------------------------------------------------- conv1 5x5
// fp32 compute (cin=3 only), writes bf16 NHWC (32ch) e1.
__global__ __launch_bounds__(256) void conv5x5_enc(
    const float* __restrict__ u, int ub_stride,
    const float* __restrict__ w,
    const float* __restrict__ gg, const float* __restrict__ bvec,
    unsigned short* __restrict__ out)
{
  __shared__ float tile[3 * 144];   // [3][12][12]
  __shared__ float ws[2400];        // (32,3,5,5)
  const int tid = threadIdx.x;
  const int b = blockIdx.y;
  const int t8 = blockIdx.x;
  const int y0 = (t8 >> 3) * 8, x0 = (t8 & 7) * 8;
  const float* ub = u + (size_t)b * ub_stride;
  for (int i = tid; i < 3 * 144; i += 256) {
    int c = i / 144, rem = i % 144;
    int r = rem / 12, cc = rem % 12;
    int y = y0 + r - 2, x = x0 + cc - 2;
    float v = 0.f;
    if (y >= 0 && y < 64 && x >= 0 && x < 64) v = ub[c * 4096 + y * 64 + x];
    tile[i] = v;
  }
  for (int i = tid; i < 2400; i += 256) ws[i] = w[i];
  __syncthreads();
  const int px = tid & 63;
  const int py = px >> 3, pxx = px & 7;
  const int ocb = (tid >> 6) * 8;
  float acc[8];
#pragma unroll
  for (int i = 0; i < 8; i++) acc[i] = 0.f;
  for (int c = 0; c < 3; c++) {
    float in25[25];
#pragma unroll
    for (int ky = 0; ky < 5; ky++)
#pragma unroll
      for (int kx = 0; kx < 5; kx++)
        in25[ky * 5 + kx] = tile[c * 144 + (py + ky) * 12 + (pxx + kx)];
#pragma unroll
    for (int o = 0; o < 8; o++) {
      float s = 0.f;
#pragma unroll
      for (int k = 0; k < 25; k++)
        s += ws[(ocb + o) * 75 + c * 25 + k] * in25[k];
      acc[o] += s;
    }
  }
  float v[8];
#pragma unroll
  for (int o = 0; o < 8; o++) {
    int oc = ocb + o;
    float t = acc[o] * (gg[oc] * BN_SCALE) + bvec[oc];
    v[o] = t > 0.f ? t : 0.f;
  }
  uint4 o4;
  o4.x = (unsigned)f2bf(v[0]) | ((unsigned)f2bf(v[1]) << 16);
  o4.y = (unsigned)f2bf(v[2]) | ((unsigned)f2bf(v[3]) << 16);
  o4.z = (unsigned)f2bf(v[4]) | ((unsigned)f2bf(v[5]) << 16);
  o4.w = (unsigned)f2bf(v[6]) | ((unsigned)f2bf(v[7]) << 16);
  *(uint4*)(out + ((size_t)b * 4096 + (size_t)(y0 + py) * 64 + (x0 + pxx)) * 32 + ocb) = o4;
}

// --------------------------------------------------- weight pre-transpose
// w (oc,cin,3,3) fp32 -> wt [tap][oc][cin] bf16
__global__ void prep_w(const float* __restrict__ src,
                       unsigned short* __restrict__ dst, int cin) {
  int i = blockIdx.x * 256 + threadIdx.x;
  int tot = 9 * 64 * cin;
  if (i >= tot) return;
  int tap = i / (64 * cin);
  int oc = (i / cin) % 64;
  int ci = i % cin;
  dst[i] = f2bf(src[(oc * cin + ci) * 9 + tap]);
}

// -------------------------------------------------- MFMA implicit-GEMM conv
// in: [NIMG][64][64][CIN] bf16 NHWC. out: [NIMG][64][64][64] bf16 NHWC.
// wt: [9][64oc][CIN] bf16, read from global (L2-resident).
// Block: 1 image x 4 output rows. 4 waves; wave w computes row y0+w (64 px x 64 oc).
// EPI 0: bn+relu; EPI 1: tanh(acc+add); EPI 2: EPI1 + fp32 NCHW d_out write.
template <int CIN, bool CIRC, int EPI>
__global__ __launch_bounds__(256) void mfma_conv(
    const unsigned short* __restrict__ in,
    const unsigned short* __restrict__ wt,
    const float* __restrict__ gg, const float* __restrict__ bvec,
    const unsigned short* __restrict__ add, int add_div,
    unsigned short* __restrict__ out,
    float* __restrict__ out2, int tstep)
{
  constexpr int CB = CIN * 2;             // bytes per pixel
  constexpr int SW = (CIN == 64) ? 7 : 3; // swizzle mask
  constexpr int KK = CIN / 32;            // K-steps of 32 per tap
  constexpr int TILE_B = 6 * 64 * CB;     // 48 KB (CIN=64) / 24 KB (CIN=32)

  __shared__ char tile[TILE_B];

  const int tid = threadIdx.x;
  const int n = blockIdx.y;
  const int y0 = blockIdx.x * 4;
  int vy = 0, vx = 0;
  if (CIRC) { int v = n % 9; vy = v / 3 - 1; vx = v % 3 - 1; }

  // stage input rows y0-1 .. y0+4 (wrapped; pad-mode rows masked in loop)
  const char* inb = (const char*)(in + (size_t)n * 4096 * CIN);
  for (int f = tid; f < TILE_B / 16; f += 256) {
    int byte = f * 16;
    int rr = byte / (64 * CB);
    int rem = byte - rr * (64 * CB);
    int px = rem / CB;
    int s = rem - px * CB;
    int gy = (y0 + rr - 1 + vy) & 63;
    f32x4 v = *(const f32x4*)(inb + (size_t)(gy * 64 + px) * CB + s);
    *(f32x4*)(tile + (rr * 64 + px) * CB + (s ^ ((px & SW) << 4))) = v;
  }
  __syncthreads();

  const int l = tid & 63;
  const int w = tid >> 6;          // wave id = output row within block
  const int l15 = l & 15;
  const int lhi = l >> 4;

  f32x4 acc[4][4];                 // [pt = 16-px col tile][ot = 16-oc tile]
#pragma unroll
  for (int i = 0; i < 4; i++)
#pragma unroll
    for (int j = 0; j < 4; j++) acc[i][j] = (f32x4){0.f, 0.f, 0.f, 0.f};

  for (int tap = 0; tap < 9; ++tap) {
    const int dy = tap / 3, dx = tap % 3;
    const int rr = w + dy;                       // tile row 0..5
    const bool yok = CIRC || ((unsigned)(y0 + w + dy - 1) < 64u);
#pragma unroll
    for (int kk = 0; kk < KK; ++kk) {
      // A-fragments (weights) straight from global/L2
      const unsigned short* wp = wt + tap * 64 * CIN + (size_t)l15 * CIN + kk * 32 + lhi * 8;
      short8 a[4];
#pragma unroll
      for (int ot = 0; ot < 4; ++ot)
        a[ot] = *(const short8*)(wp + ot * 16 * CIN);
      const int kb = kk * 64 + lhi * 16;         // byte offset in pixel
#pragma unroll
      for (int pt = 0; pt < 4; ++pt) {
        const int x = pt * 16 + l15;
        const int xr = x + dx - 1 + vx;
        const int xm = xr & 63;
        short8 pf = *(const short8*)(tile + (rr * 64 + xm) * CB +
                                     (kb ^ ((xm & SW) << 4)));
        if (!CIRC) {
          if (!(yok && (unsigned)xr < 64u)) pf ^= pf;
        }
#pragma unroll
        for (int ot = 0; ot < 4; ++ot)
          acc[pt][ot] = __builtin_amdgcn_mfma_f32_16x16x32_bf16(
              a[ot], pf, acc[pt][ot], 0, 0, 0);
      }
    }
  }

  // epilogue: lane holds 4 consecutive oc at one pixel per (pt,ot)
  const size_t nimg_off = (size_t)n * 4096 * 64;
  const unsigned short* addb =
      (EPI != 0) ? add + (size_t)(n / add_div) * 4096 * 64 : nullptr;
  int bidx = 0, vidx = 0;
  if (EPI == 2) { bidx = n / 9; vidx = n % 9; }

  const int y = y0 + w;
#pragma unroll
  for (int pt = 0; pt < 4; ++pt) {
    const int x = pt * 16 + l15;
    const int pix = y * 64 + x;
#pragma unroll
    for (int ot = 0; ot < 4; ++ot) {
      const int oc0 = ot * 16 + lhi * 4;
      float v[4];
      if constexpr (EPI == 0) {
        const f32x4 g4 = *(const f32x4*)(gg + oc0);
        const f32x4 b4 = *(const f32x4*)(bvec + oc0);
#pragma unroll
        for (int j = 0; j < 4; j++) {
          float t = acc[pt][ot][j] * (g4[j] * BN_SCALE) + b4[j];
          v[j] = t > 0.f ? t : 0.f;
        }
      } else {
        const uint2 ad = *(const uint2*)(addb + (size_t)pix * 64 + oc0);
        v[0] = fast_tanh(acc[pt][ot][0] + bf2f((unsigned short)(ad.x & 0xffff)));
        v[1] = fast_tanh(acc[pt][ot][1] + bf2f((unsigned short)(ad.x >> 16)));
        v[2] = fast_tanh(acc[pt][ot][2] + bf2f((unsigned short)(ad.y & 0xffff)));
        v[3] = fast_tanh(acc[pt][ot][3] + bf2f((unsigned short)(ad.y >> 16)));
      }
      uint2 o;
      o.x = (unsigned)f2bf(v[0]) | ((unsigned)f2bf(v[1]) << 16);
      o.y = (unsigned)f2bf(v[2]) | ((unsigned)f2bf(v[3]) << 16);
      *(uint2*)(out + nimg_off + (size_t)pix * 64 + oc0) = o;
      if constexpr (EPI == 2) {
        float* o2 = out2 +
            ((((size_t)(vidx * 4 + bidx) * 64 + oc0) * 8 + tstep) * 4096) + pix;
#pragma unroll
        for (int j = 0; j < 4; j++) o2[(size_t)j * 8 * 4096] = v[j];
      }
    }
  }
}

// --------------------------------------------------------------------- host
extern "C" void kernel_launch(void* const* d_in, const int* in_sizes, int n_in,
                              void* d_out, int out_size, void* d_ws, size_t ws_size,
                              hipStream_t stream) {
  (void)in_sizes; (void)n_in; (void)out_size; (void)ws_size;
  const float* u    = (const float*)d_in[0];
  const float* w_u1 = (const float*)d_in[1];
  const float* g1   = (const float*)d_in[2];
  const float* b1   = (const float*)d_in[3];
  const float* w_u2 = (const float*)d_in[4];
  const float* g2   = (const float*)d_in[5];
  const float* b2   = (const float*)d_in[6];
  const float* w_u3 = (const float*)d_in[7];
  const float* g3   = (const float*)d_in[8];
  const float* b3   = (const float*)d_in[9];
  const float* w_ul = (const float*)d_in[10];
  const float* gul  = (const float*)d_in[11];
  const float* bul  = (const float*)d_in[12];
  const float* w_h0 = (const float*)d_in[13];
  const float* w_h1 = (const float*)d_in[14];
  float* out = (float*)d_out;

  char* p = (char*)d_ws;
  size_t off = 0;
  auto carve = [&](size_t bytes) {
    char* r = p + off;
    off += (bytes + 255) & ~(size_t)255;
    return r;
  };
  unsigned short* e1  = (unsigned short*)carve((size_t)4 * 4096 * 32 * 2);
  unsigned short* e2  = (unsigned short*)carve((size_t)4 * 4096 * 64 * 2);
  unsigned short* xb  = (unsigned short*)carve((size_t)4 * 4096 * 64 * 2);
  unsigned short* up  = (unsigned short*)carve((size_t)36 * 4096 * 64 * 2);
  unsigned short* h0a = (unsigned short*)carve((size_t)36 * 4096 * 64 * 2);
  unsigned short* h0b = (unsigned short*)carve((size_t)36 * 4096 * 64 * 2);
  unsigned short* h1a = (unsigned short*)carve((size_t)36 * 4096 * 64 * 2);
  unsigned short* h1b = (unsigned short*)carve((size_t)36 * 4096 * 64 * 2);
  unsigned short* wt2 = (unsigned short*)carve((size_t)9 * 64 * 32 * 2);
  unsigned short* wt3 = (unsigned short*)carve((size_t)9 * 64 * 64 * 2);
  unsigned short* wtl = (unsigned short*)carve((size_t)9 * 64 * 64 * 2);
  unsigned short* wt0 = (unsigned short*)carve((size_t)9 * 64 * 64 * 2);
  unsigned short* wt1 = (unsigned short*)carve((size_t)9 * 64 * 64 * 2);

  // zero initial recurrent states (harness poisons d_ws each call)
  hipMemsetAsync(h0a, 0, (size_t)36 * 4096 * 64 * 2, stream);
  hipMemsetAsync(h1a, 0, (size_t)36 * 4096 * 64 * 2, stream);

  // weight transposes
  prep_w<<<dim3(72), dim3(256), 0, stream>>>(w_u2, wt2, 32);
  prep_w<<<dim3(144), dim3(256), 0, stream>>>(w_u3, wt3, 64);
  prep_w<<<dim3(144), dim3(256), 0, stream>>>(w_ul, wtl, 64);
  prep_w<<<dim3(144), dim3(256), 0, stream>>>(w_h0, wt0, 64);
  prep_w<<<dim3(144), dim3(256), 0, stream>>>(w_h1, wt1, 64);

  for (int t = 0; t < 8; ++t) {
    unsigned short* h0o = (t & 1) ? h0b : h0a;
    unsigned short* h0n = (t & 1) ? h0a : h0b;
    unsigned short* h1o = (t & 1) ? h1b : h1a;
    unsigned short* h1n = (t & 1) ? h1a : h1b;

    conv5x5_enc<<<dim3(64, 4), dim3(256), 0, stream>>>(
        u + (size_t)t * 3 * 4096, 8 * 3 * 4096, w_u1, g1, b1, e1);
    mfma_conv<32, false, 0><<<dim3(16, 4), dim3(256), 0, stream>>>(
        e1, wt2, g2, b2, nullptr, 1, e2, nullptr, 0);
    mfma_conv<64, false, 0><<<dim3(16, 4), dim3(256), 0, stream>>>(
        e2, wt3, g3, b3, nullptr, 1, xb, nullptr, 0);
    mfma_conv<64, true, 1><<<dim3(16, 36), dim3(256), 0, stream>>>(
        h0o, wt0, nullptr, nullptr, xb, 9, h0n, nullptr, 0);
    mfma_conv<64, false, 0><<<dim3(16, 36), dim3(256), 0, stream>>>(
        h0n, wtl, gul, bul, nullptr, 1, up, nullptr, 0);
    mfma_conv<64, true, 2><<<dim3(16, 36), dim3(256), 0, stream>>>(
        h1o, wt1, nullptr, nullptr, up, 1, h1n, out, t);
  }
}

// Round 4
// 1326.528 us; speedup vs baseline: 7.5145x; 1.2504x over previous
//
#include <hip/hip_runtime.h>
#include <hip/hip_bf16.h>
#include <math.h>

typedef __attribute__((ext_vector_type(8))) short short8;
typedef __attribute__((ext_vector_type(4))) float f32x4;

#define BN_SCALE 0.9999950000374997f  // 1/sqrt(1+1e-5)

__device__ __forceinline__ unsigned short f2bf(float f) {
  union { float f; unsigned u; } v; v.f = f;
  unsigned r = v.u + 0x7fff + ((v.u >> 16) & 1);
  return (unsigned short)(r >> 16);
}
__device__ __forceinline__ float bf2f(unsigned short h) {
  union { unsigned u; float f; } v; v.u = ((unsigned)h) << 16;
  return v.f;
}
__device__ __forceinline__ float fast_tanh(float x) {
  float e = __expf(2.0f * x);
  return 1.0f - 2.0f / (e + 1.0f);
}

// ---------------------------------------------------------------- conv1 5x5
// fp32 compute (cin=3), batched over all 32 (b,t) images. Writes bf16 NHWC.
__global__ __launch_bounds__(256) void conv5x5_enc(
    const float* __restrict__ u, int ub_stride,
    const float* __restrict__ w,
    const float* __restrict__ gg, const float* __restrict__ bvec,
    unsigned short* __restrict__ out)
{
  __shared__ float tile[3 * 144];   // [3][12][12]
  __shared__ float ws[2400];        // (32,3,5,5)
  const int tid = threadIdx.x;
  const int img = blockIdx.y;
  const int t8 = blockIdx.x;
  const int y0 = (t8 >> 3) * 8, x0 = (t8 & 7) * 8;
  const float* ub = u + (size_t)img * ub_stride;
  for (int i = tid; i < 3 * 144; i += 256) {
    int c = i / 144, rem = i % 144;
    int r = rem / 12, cc = rem % 12;
    int y = y0 + r - 2, x = x0 + cc - 2;
    float v = 0.f;
    if (y >= 0 && y < 64 && x >= 0 && x < 64) v = ub[c * 4096 + y * 64 + x];
    tile[i] = v;
  }
  for (int i = tid; i < 2400; i += 256) ws[i] = w[i];
  __syncthreads();
  const int px = tid & 63;
  const int py = px >> 3, pxx = px & 7;
  const int ocb = (tid >> 6) * 8;
  float acc[8];
#pragma unroll
  for (int i = 0; i < 8; i++) acc[i] = 0.f;
  for (int c = 0; c < 3; c++) {
    float in25[25];
#pragma unroll
    for (int ky = 0; ky < 5; ky++)
#pragma unroll
      for (int kx = 0; kx < 5; kx++)
        in25[ky * 5 + kx] = tile[c * 144 + (py + ky) * 12 + (pxx + kx)];
#pragma unroll
    for (int o = 0; o < 8; o++) {
      float s = 0.f;
#pragma unroll
      for (int k = 0; k < 25; k++)
        s += ws[(ocb + o) * 75 + c * 25 + k] * in25[k];
      acc[o] += s;
    }
  }
  float v[8];
#pragma unroll
  for (int o = 0; o < 8; o++) {
    int oc = ocb + o;
    float t = acc[o] * (gg[oc] * BN_SCALE) + bvec[oc];
    v[o] = t > 0.f ? t : 0.f;
  }
  uint4 o4;
  o4.x = (unsigned)f2bf(v[0]) | ((unsigned)f2bf(v[1]) << 16);
  o4.y = (unsigned)f2bf(v[2]) | ((unsigned)f2bf(v[3]) << 16);
  o4.z = (unsigned)f2bf(v[4]) | ((unsigned)f2bf(v[5]) << 16);
  o4.w = (unsigned)f2bf(v[6]) | ((unsigned)f2bf(v[7]) << 16);
  *(uint4*)(out + ((size_t)img * 4096 + (size_t)(y0 + py) * 64 + (x0 + pxx)) * 32 + ocb) = o4;
}

// --------------------------------------------------- weight pre-transpose
// w (64oc,cin,3,3) fp32 -> wt [tap][64oc][cin] bf16
__global__ void prep_w(const float* __restrict__ src,
                       unsigned short* __restrict__ dst, int cin) {
  int i = blockIdx.x * 256 + threadIdx.x;
  int tot = 9 * 64 * cin;
  if (i >= tot) return;
  int tap = i / (64 * cin);
  int oc = (i / cin) % 64;
  int ci = i % cin;
  dst[i] = f2bf(src[(oc * cin + ci) * 9 + tap]);
}

// -------------------------------------------------- MFMA implicit-GEMM conv
// in: [NIMG][64][64][CIN] bf16 NHWC. out: [NIMG][64][64][64] bf16 NHWC.
// wt: [9][64oc][CIN] bf16, read from global (L2-resident).
// Block: 1 image x 4 output rows; wave w computes row y0+w (64 px x 64 oc).
// EPI 0: bn+relu; EPI 1: tanh(acc+add).
template <int CIN, bool CIRC, int EPI>
__global__ __launch_bounds__(256) void mfma_conv(
    const unsigned short* __restrict__ in,
    const unsigned short* __restrict__ wt,
    const float* __restrict__ gg, const float* __restrict__ bvec,
    const unsigned short* __restrict__ add, int add_div, int add_bstride,
    unsigned short* __restrict__ out)
{
  constexpr int CB = CIN * 2;
  constexpr int SW = (CIN == 64) ? 7 : 3;
  constexpr int KK = CIN / 32;
  constexpr int TILE_B = 6 * 64 * CB;

  __shared__ char tile[TILE_B];

  const int tid = threadIdx.x;
  const int n = blockIdx.y;
  const int y0 = blockIdx.x * 4;
  int vy = 0, vx = 0;
  if (CIRC) { int v = n % 9; vy = v / 3 - 1; vx = v % 3 - 1; }

  const char* inb = (const char*)(in + (size_t)n * 4096 * CIN);
  for (int f = tid; f < TILE_B / 16; f += 256) {
    int byte = f * 16;
    int rr = byte / (64 * CB);
    int rem = byte - rr * (64 * CB);
    int px = rem / CB;
    int s = rem - px * CB;
    int gy = (y0 + rr - 1 + vy) & 63;
    f32x4 v = *(const f32x4*)(inb + (size_t)(gy * 64 + px) * CB + s);
    *(f32x4*)(tile + (rr * 64 + px) * CB + (s ^ ((px & SW) << 4))) = v;
  }
  __syncthreads();

  const int l = tid & 63;
  const int w = tid >> 6;
  const int l15 = l & 15;
  const int lhi = l >> 4;

  f32x4 acc[4][4];
#pragma unroll
  for (int i = 0; i < 4; i++)
#pragma unroll
    for (int j = 0; j < 4; j++) acc[i][j] = (f32x4){0.f, 0.f, 0.f, 0.f};

  for (int tap = 0; tap < 9; ++tap) {
    const int dy = tap / 3, dx = tap % 3;
    const int rr = w + dy;
    const bool yok = CIRC || ((unsigned)(y0 + w + dy - 1) < 64u);
#pragma unroll
    for (int kk = 0; kk < KK; ++kk) {
      const unsigned short* wp = wt + tap * 64 * CIN + (size_t)l15 * CIN + kk * 32 + lhi * 8;
      short8 a[4];
#pragma unroll
      for (int ot = 0; ot < 4; ++ot)
        a[ot] = *(const short8*)(wp + ot * 16 * CIN);
      const int kb = kk * 64 + lhi * 16;
#pragma unroll
      for (int pt = 0; pt < 4; ++pt) {
        const int x = pt * 16 + l15;
        const int xr = x + dx - 1 + vx;
        const int xm = xr & 63;
        short8 pf = *(const short8*)(tile + (rr * 64 + xm) * CB +
                                     (kb ^ ((xm & SW) << 4)));
        if (!CIRC) {
          if (!(yok && (unsigned)xr < 64u)) pf ^= pf;
        }
#pragma unroll
        for (int ot = 0; ot < 4; ++ot)
          acc[pt][ot] = __builtin_amdgcn_mfma_f32_16x16x32_bf16(
              a[ot], pf, acc[pt][ot], 0, 0, 0);
      }
    }
  }

  const size_t nimg_off = (size_t)n * 4096 * 64;
  const unsigned short* addb =
      (EPI != 0) ? add + (size_t)(n / add_div) * add_bstride : nullptr;

  const int y = y0 + w;
#pragma unroll
  for (int pt = 0; pt < 4; ++pt) {
    const int x = pt * 16 + l15;
    const int pix = y * 64 + x;
#pragma unroll
    for (int ot = 0; ot < 4; ++ot) {
      const int oc0 = ot * 16 + lhi * 4;
      float v[4];
      if constexpr (EPI == 0) {
        const f32x4 g4 = *(const f32x4*)(gg + oc0);
        const f32x4 b4 = *(const f32x4*)(bvec + oc0);
#pragma unroll
        for (int j = 0; j < 4; j++) {
          float t = acc[pt][ot][j] * (g4[j] * BN_SCALE) + b4[j];
          v[j] = t > 0.f ? t : 0.f;
        }
      } else {
        const uint2 ad = *(const uint2*)(addb + (size_t)pix * 64 + oc0);
        v[0] = fast_tanh(acc[pt][ot][0] + bf2f((unsigned short)(ad.x & 0xffff)));
        v[1] = fast_tanh(acc[pt][ot][1] + bf2f((unsigned short)(ad.x >> 16)));
        v[2] = fast_tanh(acc[pt][ot][2] + bf2f((unsigned short)(ad.y & 0xffff)));
        v[3] = fast_tanh(acc[pt][ot][3] + bf2f((unsigned short)(ad.y >> 16)));
      }
      uint2 o;
      o.x = (unsigned)f2bf(v[0]) | ((unsigned)f2bf(v[1]) << 16);
      o.y = (unsigned)f2bf(v[2]) | ((unsigned)f2bf(v[3]) << 16);
      *(uint2*)(out + nimg_off + (size_t)pix * 64 + oc0) = o;
    }
  }
}

// ------------------------------------------- fused up-conv + h1 update
// up = relu(bn(conv_zp(h0, wul))) computed into fp32 acc; h1 circconv
// MFMA-accumulates on top (C-operand seeding); tanh; dual write:
// h1new bf16 NHWC + d_out fp32 (V,B,C,T,H,W).
__global__ __launch_bounds__(256) void fused_up_h1(
    const unsigned short* __restrict__ h0,
    const unsigned short* __restrict__ h1old,
    const unsigned short* __restrict__ wul,
    const unsigned short* __restrict__ wh1,
    const float* __restrict__ gg, const float* __restrict__ bvec,
    unsigned short* __restrict__ h1new,
    float* __restrict__ out2, int tstep)
{
  __shared__ char tile[6 * 64 * 128];

  const int tid = threadIdx.x;
  const int n = blockIdx.y;
  const int b = n / 9, v = n % 9;
  const int vy = v / 3 - 1, vx = v % 3 - 1;
  const int y0 = blockIdx.x * 4;
  const int l = tid & 63;
  const int w = tid >> 6;
  const int l15 = l & 15;
  const int lhi = l >> 4;

  // ---- phase 1: stage h0 rows (unshifted), zero-pad conv with wul
  {
    const char* inb = (const char*)(h0 + (size_t)n * 4096 * 64);
    for (int f = tid; f < 6 * 64 * 128 / 16; f += 256) {
      int byte = f * 16;
      int rr = byte / (64 * 128);
      int rem = byte - rr * (64 * 128);
      int px = rem / 128;
      int s = rem - px * 128;
      int gy = (y0 + rr - 1) & 63;
      f32x4 vv = *(const f32x4*)(inb + (size_t)(gy * 64 + px) * 128 + s);
      *(f32x4*)(tile + (rr * 64 + px) * 128 + (s ^ ((px & 7) << 4))) = vv;
    }
  }
  __syncthreads();

  f32x4 acc[4][4];
#pragma unroll
  for (int i = 0; i < 4; i++)
#pragma unroll
    for (int j = 0; j < 4; j++) acc[i][j] = (f32x4){0.f, 0.f, 0.f, 0.f};

  for (int tap = 0; tap < 9; ++tap) {
    const int dy = tap / 3, dx = tap % 3;
    const int rr = w + dy;
    const bool yok = (unsigned)(y0 + w + dy - 1) < 64u;
#pragma unroll
    for (int kk = 0; kk < 2; ++kk) {
      const unsigned short* wp = wul + tap * 64 * 64 + (size_t)l15 * 64 + kk * 32 + lhi * 8;
      short8 a[4];
#pragma unroll
      for (int ot = 0; ot < 4; ++ot)
        a[ot] = *(const short8*)(wp + ot * 16 * 64);
      const int kb = kk * 64 + lhi * 16;
#pragma unroll
      for (int pt = 0; pt < 4; ++pt) {
        const int x = pt * 16 + l15;
        const int xr = x + dx - 1;
        const int xm = xr & 63;
        short8 pf = *(const short8*)(tile + (rr * 64 + xm) * 128 +
                                     (kb ^ ((xm & 7) << 4)));
        if (!(yok && (unsigned)xr < 64u)) pf ^= pf;
#pragma unroll
        for (int ot = 0; ot < 4; ++ot)
          acc[pt][ot] = __builtin_amdgcn_mfma_f32_16x16x32_bf16(
              a[ot], pf, acc[pt][ot], 0, 0, 0);
      }
    }
  }

  // bn + relu in fp32 registers: acc now holds `up`
  {
    f32x4 g4[4], b4[4];
#pragma unroll
    for (int ot = 0; ot < 4; ++ot) {
      g4[ot] = *(const f32x4*)(gg + ot * 16 + lhi * 4);
      b4[ot] = *(const f32x4*)(bvec + ot * 16 + lhi * 4);
    }
#pragma unroll
    for (int pt = 0; pt < 4; ++pt)
#pragma unroll
      for (int ot = 0; ot < 4; ++ot)
#pragma unroll
        for (int j = 0; j < 4; j++) {
          float t = acc[pt][ot][j] * (g4[ot][j] * BN_SCALE) + b4[ot][j];
          acc[pt][ot][j] = t > 0.f ? t : 0.f;
        }
  }

  // ---- phase 2: restage with h1old (velocity-shifted rows), circular conv
  __syncthreads();
  {
    const char* inb = (const char*)(h1old + (size_t)n * 4096 * 64);
    for (int f = tid; f < 6 * 64 * 128 / 16; f += 256) {
      int byte = f * 16;
      int rr = byte / (64 * 128);
      int rem = byte - rr * (64 * 128);
      int px = rem / 128;
      int s = rem - px * 128;
      int gy = (y0 + rr - 1 + vy) & 63;
      f32x4 vv = *(const f32x4*)(inb + (size_t)(gy * 64 + px) * 128 + s);
      *(f32x4*)(tile + (rr * 64 + px) * 128 + (s ^ ((px & 7) << 4))) = vv;
    }
  }
  __syncthreads();

  for (int tap = 0; tap < 9; ++tap) {
    const int dy = tap / 3, dx = tap % 3;
    const int rr = w + dy;
#pragma unroll
    for (int kk = 0; kk < 2; ++kk) {
      const unsigned short* wp = wh1 + tap * 64 * 64 + (size_t)l15 * 64 + kk * 32 + lhi * 8;
      short8 a[4];
#pragma unroll
      for (int ot = 0; ot < 4; ++ot)
        a[ot] = *(const short8*)(wp + ot * 16 * 64);
      const int kb = kk * 64 + lhi * 16;
#pragma unroll
      for (int pt = 0; pt < 4; ++pt) {
        const int x = pt * 16 + l15;
        const int xm = (x + dx - 1 + vx) & 63;
        short8 pf = *(const short8*)(tile + (rr * 64 + xm) * 128 +
                                     (kb ^ ((xm & 7) << 4)));
#pragma unroll
        for (int ot = 0; ot < 4; ++ot)
          acc[pt][ot] = __builtin_amdgcn_mfma_f32_16x16x32_bf16(
              a[ot], pf, acc[pt][ot], 0, 0, 0);
      }
    }
  }

  // ---- epilogue: tanh, dual write
  const size_t nimg_off = (size_t)n * 4096 * 64;
  const int y = y0 + w;
#pragma unroll
  for (int pt = 0; pt < 4; ++pt) {
    const int x = pt * 16 + l15;
    const int pix = y * 64 + x;
#pragma unroll
    for (int ot = 0; ot < 4; ++ot) {
      const int oc0 = ot * 16 + lhi * 4;
      float vo[4];
#pragma unroll
      for (int j = 0; j < 4; j++) vo[j] = fast_tanh(acc[pt][ot][j]);
      uint2 o;
      o.x = (unsigned)f2bf(vo[0]) | ((unsigned)f2bf(vo[1]) << 16);
      o.y = (unsigned)f2bf(vo[2]) | ((unsigned)f2bf(vo[3]) << 16);
      *(uint2*)(h1new + nimg_off + (size_t)pix * 64 + oc0) = o;
      float* o2 = out2 +
          ((((size_t)(v * 4 + b) * 64 + oc0) * 8 + tstep) * 4096) + pix;
#pragma unroll
      for (int j = 0; j < 4; j++) o2[(size_t)j * 8 * 4096] = vo[j];
    }
  }
}

// --------------------------------------------------------------------- host
extern "C" void kernel_launch(void* const* d_in, const int* in_sizes, int n_in,
                              void* d_out, int out_size, void* d_ws, size_t ws_size,
                              hipStream_t stream) {
  (void)in_sizes; (void)n_in; (void)out_size; (void)ws_size;
  const float* u    = (const float*)d_in[0];
  const float* w_u1 = (const float*)d_in[1];
  const float* g1   = (const float*)d_in[2];
  const float* b1   = (const float*)d_in[3];
  const float* w_u2 = (const float*)d_in[4];
  const float* g2   = (const float*)d_in[5];
  const float* b2   = (const float*)d_in[6];
  const float* w_u3 = (const float*)d_in[7];
  const float* g3   = (const float*)d_in[8];
  const float* b3   = (const float*)d_in[9];
  const float* w_ul = (const float*)d_in[10];
  const float* gul  = (const float*)d_in[11];
  const float* bul  = (const float*)d_in[12];
  const float* w_h0 = (const float*)d_in[13];
  const float* w_h1 = (const float*)d_in[14];
  float* out = (float*)d_out;

  char* p = (char*)d_ws;
  size_t off = 0;
  auto carve = [&](size_t bytes) {
    char* r = p + off;
    off += (bytes + 255) & ~(size_t)255;
    return r;
  };
  unsigned short* e1  = (unsigned short*)carve((size_t)32 * 4096 * 32 * 2);
  unsigned short* e2  = (unsigned short*)carve((size_t)32 * 4096 * 64 * 2);
  unsigned short* xb  = (unsigned short*)carve((size_t)32 * 4096 * 64 * 2);
  unsigned short* h0a = (unsigned short*)carve((size_t)36 * 4096 * 64 * 2);
  unsigned short* h0b = (unsigned short*)carve((size_t)36 * 4096 * 64 * 2);
  unsigned short* h1a = (unsigned short*)carve((size_t)36 * 4096 * 64 * 2);
  unsigned short* h1b = (unsigned short*)carve((size_t)36 * 4096 * 64 * 2);
  unsigned short* wt2 = (unsigned short*)carve((size_t)9 * 64 * 32 * 2);
  unsigned short* wt3 = (unsigned short*)carve((size_t)9 * 64 * 64 * 2);
  unsigned short* wtl = (unsigned short*)carve((size_t)9 * 64 * 64 * 2);
  unsigned short* wt0 = (unsigned short*)carve((size_t)9 * 64 * 64 * 2);
  unsigned short* wt1 = (unsigned short*)carve((size_t)9 * 64 * 64 * 2);

  // zero initial recurrent states (d_ws is poisoned before every call)
  hipMemsetAsync(h0a, 0, (size_t)36 * 4096 * 64 * 2, stream);
  hipMemsetAsync(h1a, 0, (size_t)36 * 4096 * 64 * 2, stream);

  // weight transposes
  prep_w<<<dim3(72), dim3(256), 0, stream>>>(w_u2, wt2, 32);
  prep_w<<<dim3(144), dim3(256), 0, stream>>>(w_u3, wt3, 64);
  prep_w<<<dim3(144), dim3(256), 0, stream>>>(w_ul, wtl, 64);
  prep_w<<<dim3(144), dim3(256), 0, stream>>>(w_h0, wt0, 64);
  prep_w<<<dim3(144), dim3(256), 0, stream>>>(w_h1, wt1, 64);

  // batched encoder over all 32 (b,t) images: img = b*8 + t (u's layout)
  conv5x5_enc<<<dim3(64, 32), dim3(256), 0, stream>>>(
      u, 3 * 4096, w_u1, g1, b1, e1);
  mfma_conv<32, false, 0><<<dim3(16, 32), dim3(256), 0, stream>>>(
      e1, wt2, g2, b2, nullptr, 1, 0, e2);
  mfma_conv<64, false, 0><<<dim3(16, 32), dim3(256), 0, stream>>>(
      e2, wt3, g3, b3, nullptr, 1, 0, xb);

  for (int t = 0; t < 8; ++t) {
    unsigned short* h0o = (t & 1) ? h0b : h0a;
    unsigned short* h0n = (t & 1) ? h0a : h0b;
    unsigned short* h1o = (t & 1) ? h1b : h1a;
    unsigned short* h1n = (t & 1) ? h1a : h1b;

    // h0 = tanh(x[b,t] + circconv(h0_old)); add index = (n/9)*8stride + t
    mfma_conv<64, true, 1><<<dim3(16, 36), dim3(256), 0, stream>>>(
        h0o, wt0, nullptr, nullptr, xb + (size_t)t * 4096 * 64, 9,
        8 * 4096 * 64, h0n);

    fused_up_h1<<<dim3(16, 36), dim3(256), 0, stream>>>(
        h0n, h1o, wtl, wt1, gul, bul, h1n, out, t);
  }
}